// Round 1
// baseline (729.509 us; speedup 1.0000x reference)
//
#include <hip/hip_runtime.h>
#include <cstdint>
#include <cstddef>

// Problem constants
#define BB 4
#define SS 4096
#define DD 256
#define SCORE_SCALE (1.0f/16.0f)   // 1/sqrt(256)
#define PIW 0.5f
#define NROWS (BB * SS)            // 16384 flattened rows

typedef float          f32x4  __attribute__((ext_vector_type(4)));
typedef __bf16         bf16v8 __attribute__((ext_vector_type(8)));
typedef unsigned short u16v8  __attribute__((ext_vector_type(8)));
typedef unsigned short u16v4  __attribute__((ext_vector_type(4)));

__device__ __forceinline__ f32x4 mfma_bf16(u16v8 a, u16v8 b, f32x4 c) {
    return __builtin_amdgcn_mfma_f32_16x16x32_bf16(
        __builtin_bit_cast(bf16v8, a), __builtin_bit_cast(bf16v8, b), c, 0, 0, 0);
}

__device__ __forceinline__ unsigned short f2bf(float f) {
    unsigned u = __float_as_uint(f);
    u += 0x7FFFu + ((u >> 16) & 1u);           // RNE (inputs finite)
    return (unsigned short)(u >> 16);
}
__device__ __forceinline__ float bf2f(unsigned short h) {
    return __uint_as_float(((unsigned)h) << 16);
}
__device__ __forceinline__ unsigned fenc(float x) {
    unsigned u = __float_as_uint(x);
    return (u & 0x80000000u) ? ~u : (u | 0x80000000u);
}
__device__ __forceinline__ float fdec(unsigned e) {
    return __uint_as_float((e & 0x80000000u) ? (e ^ 0x80000000u) : ~e);
}

// ---------------------------------------------------------------------------
// Projections (fp32 vector GEMM, precision-critical): C = A[16384,256]@W[256,256].
// z=0: qh/ql bf16 split. z=1: kh/kl split. z=2: vT bf16 transposed [B][D][S].
// Also inits gmax.
// ---------------------------------------------------------------------------
#define TM 128
#define TN 128
#define TK 16
#define PADW 132

__global__ __launch_bounds__(256) void proj_kernel(
    const float* __restrict__ query, const float* __restrict__ key_, const float* __restrict__ value,
    const float* __restrict__ Wq, const float* __restrict__ Wk, const float* __restrict__ Wv,
    unsigned short* __restrict__ qh, unsigned short* __restrict__ ql,
    unsigned short* __restrict__ kh, unsigned short* __restrict__ kl,
    unsigned short* __restrict__ vT, unsigned* __restrict__ gmax)
{
    const int z = blockIdx.z;
    const float* A = (z == 0) ? query : (z == 1) ? key_ : value;
    const float* W = (z == 0) ? Wq    : (z == 1) ? Wk   : Wv;
    if (z == 0 && blockIdx.x == 0 && blockIdx.y == 0 && threadIdx.x == 0)
        *gmax = 0x007FFFFFu;   // fenc(-inf)

    const int K = DD, N = DD;
    __shared__ float As[TK][PADW];
    __shared__ float Bs[TK][PADW];
    const int tid = threadIdx.x;
    const int tx = tid & 15, ty = tid >> 4;
    const int rowBase = blockIdx.y * TM;   // flattened B*S row
    const int colBase = blockIdx.x * TN;

    float acc[8][8] = {};

    for (int k0 = 0; k0 < K; k0 += TK) {
        #pragma unroll
        for (int i = 0; i < 2; i++) {
            int idx = tid + i * 256;
            int r = idx >> 2, kq = idx & 3;
            const float4 av = *(const float4*)&A[(size_t)(rowBase + r) * K + k0 + kq * 4];
            As[kq * 4 + 0][r] = av.x; As[kq * 4 + 1][r] = av.y;
            As[kq * 4 + 2][r] = av.z; As[kq * 4 + 3][r] = av.w;
        }
        #pragma unroll
        for (int i = 0; i < 2; i++) {
            int idx = tid + i * 256;
            int kk = idx >> 5, cq = idx & 31;
            *(float4*)&Bs[kk][cq * 4] = *(const float4*)&W[(size_t)(k0 + kk) * N + colBase + cq * 4];
        }
        __syncthreads();
        #pragma unroll
        for (int kk = 0; kk < TK; kk++) {
            float a[8], b[8];
            *(float4*)&a[0] = *(const float4*)&As[kk][ty * 8];
            *(float4*)&a[4] = *(const float4*)&As[kk][ty * 8 + 4];
            *(float4*)&b[0] = *(const float4*)&Bs[kk][tx * 8];
            *(float4*)&b[4] = *(const float4*)&Bs[kk][tx * 8 + 4];
            #pragma unroll
            for (int i = 0; i < 8; i++)
                #pragma unroll
                for (int j = 0; j < 8; j++)
                    acc[i][j] = fmaf(a[i], b[j], acc[i][j]);
        }
        __syncthreads();
    }

    #pragma unroll
    for (int i = 0; i < 8; i++) {
        const int gr = rowBase + ty * 8 + i;           // flattened B*S row
        if (z == 2) {
            const int b2 = gr >> 12, s2 = gr & (SS - 1);
            #pragma unroll
            for (int j = 0; j < 8; j++) {
                int col = colBase + tx * 8 + j;
                vT[((size_t)b2 * DD + col) * SS + s2] = f2bf(acc[i][j]);
            }
        } else {
            unsigned short h[8], l[8];
            #pragma unroll
            for (int j = 0; j < 8; j++) {
                h[j] = f2bf(acc[i][j]);
                l[j] = f2bf(acc[i][j] - bf2f(h[j]));
            }
            unsigned short* H = (z == 0) ? qh : kh;
            unsigned short* L = (z == 0) ? ql : kl;
            size_t base = (size_t)gr * DD + colBase + tx * 8;
            *(u16v4*)&H[base]     = (u16v4){h[0], h[1], h[2], h[3]};
            *(u16v4*)&H[base + 4] = (u16v4){h[4], h[5], h[6], h[7]};
            *(u16v4*)&L[base]     = (u16v4){l[0], l[1], l[2], l[3]};
            *(u16v4*)&L[base + 4] = (u16v4){l[4], l[5], l[6], l[7]};
        }
    }
}

// ---------------------------------------------------------------------------
// Scores: C = (q@k^T)/16 via split-bf16 MFMA: qh*kh + qh*kl + ql*kh.
// 128x128 C-tile, 4 waves (2x2 of 64x64), BK=32.
// Epilogue: per-row (max, sumexp) over this 128-col tile -> tmaxg/tsumg,
// plus block max -> gmax. All computed from register-resident acc.
// ---------------------------------------------------------------------------
#define SPAD 40   // 32 + 8 bf16 LDS row stride

__global__ __launch_bounds__(256) void scores_mfma(
    const unsigned short* __restrict__ qh, const unsigned short* __restrict__ ql,
    const unsigned short* __restrict__ kh, const unsigned short* __restrict__ kl,
    float* __restrict__ attn, unsigned* __restrict__ gmax,
    float* __restrict__ tmaxg, float* __restrict__ tsumg)
{
    const int b = blockIdx.z;
    const size_t boff = (size_t)b * SS * DD;
    const unsigned short* Qh = qh + boff;
    const unsigned short* Ql = ql + boff;
    const unsigned short* Kh = kh + boff;
    const unsigned short* Kl = kl + boff;
    float* C = attn + (size_t)b * SS * SS;

    __shared__ unsigned short Ah[128][SPAD];
    __shared__ unsigned short Al[128][SPAD];
    __shared__ unsigned short Bh[128][SPAD];
    __shared__ unsigned short Bl[128][SPAD];
    __shared__ float s_m[4][64];
    __shared__ float s_s[4][64];
    __shared__ float red[128];

    const int tid = threadIdx.x;
    const int lane = tid & 63, w = tid >> 6;
    const int wr = (w >> 1) * 64, wc = (w & 1) * 64;
    const int m = lane & 15, qq = lane >> 4;
    const int rowBase = blockIdx.y * 128;
    const int colBase = blockIdx.x * 128;

    f32x4 acc[4][4];
    #pragma unroll
    for (int i = 0; i < 4; i++)
        #pragma unroll
        for (int j = 0; j < 4; j++)
            acc[i][j] = (f32x4){0.f, 0.f, 0.f, 0.f};

    const int chunk = (tid & 3) * 8;        // bf16 offset within 32-wide k-slab
    const int srow  = tid >> 2;             // 0..63

    for (int k0 = 0; k0 < DD; k0 += 32) {
        #pragma unroll
        for (int i = 0; i < 2; i++) {
            int r = srow + i * 64;
            size_t ga = (size_t)(rowBase + r) * DD + k0 + chunk;
            size_t gb = (size_t)(colBase + r) * DD + k0 + chunk;
            *(u16v8*)&Ah[r][chunk] = *(const u16v8*)&Qh[ga];
            *(u16v8*)&Al[r][chunk] = *(const u16v8*)&Ql[ga];
            *(u16v8*)&Bh[r][chunk] = *(const u16v8*)&Kh[gb];
            *(u16v8*)&Bl[r][chunk] = *(const u16v8*)&Kl[gb];
        }
        __syncthreads();

        const int kb = qq * 8;
        u16v8 ah[4], al[4], bh[4], bl[4];
        #pragma unroll
        for (int i = 0; i < 4; i++) {
            ah[i] = *(const u16v8*)&Ah[wr + i * 16 + m][kb];
            al[i] = *(const u16v8*)&Al[wr + i * 16 + m][kb];
            bh[i] = *(const u16v8*)&Bh[wc + i * 16 + m][kb];
            bl[i] = *(const u16v8*)&Bl[wc + i * 16 + m][kb];
        }
        #pragma unroll
        for (int i = 0; i < 4; i++)
            #pragma unroll
            for (int j = 0; j < 4; j++) {
                acc[i][j] = mfma_bf16(ah[i], bh[j], acc[i][j]);
                acc[i][j] = mfma_bf16(ah[i], bl[j], acc[i][j]);
                acc[i][j] = mfma_bf16(al[i], bh[j], acc[i][j]);
            }
        __syncthreads();
    }

    // scale once; all consumers (C store, stats, gmax) use scaled values
    #pragma unroll
    for (int i = 0; i < 4; i++)
        #pragma unroll
        for (int j = 0; j < 4; j++)
            acc[i][j] *= SCORE_SCALE;

    // store raw scores
    #pragma unroll
    for (int i = 0; i < 4; i++)
        #pragma unroll
        for (int j = 0; j < 4; j++)
            #pragma unroll
            for (int r = 0; r < 4; r++) {
                int row = rowBase + wr + i * 16 + qq * 4 + r;
                int col = colBase + wc + j * 16 + m;
                C[(size_t)row * SS + col] = acc[i][j][r];
            }

    // ---- per-row tile stats (flash-style), register resident ----
    // lane holds rows wr + i*16 + qq*4 + r  at cols wc + j*16 + m
    float lmax[16];
    #pragma unroll
    for (int i = 0; i < 4; i++)
        #pragma unroll
        for (int r = 0; r < 4; r++)
            lmax[i * 4 + r] = fmaxf(fmaxf(acc[i][0][r], acc[i][1][r]),
                                    fmaxf(acc[i][2][r], acc[i][3][r]));
    #pragma unroll
    for (int t = 0; t < 16; t++) {
        #pragma unroll
        for (int msk = 1; msk < 16; msk <<= 1)
            lmax[t] = fmaxf(lmax[t], __shfl_xor(lmax[t], msk));
    }
    if (m == 0) {
        #pragma unroll
        for (int i = 0; i < 4; i++)
            #pragma unroll
            for (int r = 0; r < 4; r++)
                s_m[w][i * 16 + qq * 4 + r] = lmax[i * 4 + r];
    }
    __syncthreads();
    // combined 128-col rowmax (both wc halves), then sumexp against it
    float lsum[16];
    #pragma unroll
    for (int i = 0; i < 4; i++)
        #pragma unroll
        for (int r = 0; r < 4; r++) {
            int idx = i * 16 + qq * 4 + r;
            float rm = fmaxf(s_m[w][idx], s_m[w ^ 1][idx]);
            float s = 0.f;
            #pragma unroll
            for (int j = 0; j < 4; j++)
                s += __expf(acc[i][j][r] - rm);
            lsum[i * 4 + r] = s;
        }
    #pragma unroll
    for (int t = 0; t < 16; t++) {
        #pragma unroll
        for (int msk = 1; msk < 16; msk <<= 1)
            lsum[t] += __shfl_xor(lsum[t], msk);
    }
    if (m == 0) {
        #pragma unroll
        for (int i = 0; i < 4; i++)
            #pragma unroll
            for (int r = 0; r < 4; r++)
                s_s[w][i * 16 + qq * 4 + r] = lsum[i * 4 + r];
    }
    __syncthreads();

    if (tid < 128) {
        int wp = tid >> 6, lr = tid & 63;
        float tm = fmaxf(s_m[2 * wp][lr], s_m[2 * wp + 1][lr]);
        float ts = s_s[2 * wp][lr] + s_s[2 * wp + 1][lr];   // same reference max
        size_t gi = (size_t)blockIdx.x * NROWS + (size_t)b * SS + rowBase + tid;
        tmaxg[gi] = tm;
        tsumg[gi] = ts;
        red[tid] = tm;
    }
    __syncthreads();
    for (int s2 = 64; s2 > 0; s2 >>= 1) {
        if (tid < s2) red[tid] = fmaxf(red[tid], red[tid + s2]);
        __syncthreads();
    }
    if (tid == 0) atomicMax(gmax, fenc(red[0]));
}

// ---------------------------------------------------------------------------
// Merge per-tile stats into per-row (max, 1/sum), folding in the diag bias
// (needs final gmax). Reads 4 MB stats + 16K diag elements. Tiny.
// ---------------------------------------------------------------------------
__global__ __launch_bounds__(256) void stats_merge(
    const float* __restrict__ tmaxg, const float* __restrict__ tsumg,
    const float* __restrict__ attn, const unsigned* __restrict__ gmax,
    float* __restrict__ rowm, float* __restrict__ rowinv)
{
    const int grow = blockIdx.x * 256 + threadIdx.x;   // 0..16383
    const int b = grow >> 12, i = grow & (SS - 1);
    const float bias = PIW * fdec(*gmax);

    float tm[32];
    float mx = -INFINITY;
    #pragma unroll
    for (int t = 0; t < 32; t++) {
        tm[t] = tmaxg[(size_t)t * NROWS + grow];
        mx = fmaxf(mx, tm[t]);
    }
    const float dii = attn[(size_t)b * SS * SS + (size_t)i * SS + i];
    mx = fmaxf(mx, dii + bias);

    float s = 0.f;
    #pragma unroll
    for (int t = 0; t < 32; t++)
        s += tsumg[(size_t)t * NROWS + grow] * __expf(tm[t] - mx);
    // replace unbiased diag contribution with biased one
    s += __expf(dii + bias - mx) - __expf(dii - mx);

    rowm[grow] = mx;
    rowinv[grow] = 1.0f / s;
}

// ---------------------------------------------------------------------------
// Fused softmax + AV: reads raw scores once, normalizes (exp(x-m)/s with diag
// bias), writes fp32 weights (the attn output) AND stages bf16 into LDS for
// MFMA with pre-transposed vT. BM=32, BN=256, BK=64. Grid (128,4); 4 waves
// each own 32x64 of C.
// ---------------------------------------------------------------------------
#define APAD 72   // 64 + 8 bf16 LDS row stride

__global__ __launch_bounds__(256) void av_softmax_mfma(
    float* __restrict__ attn, const unsigned short* __restrict__ vT,
    const float* __restrict__ rowm, const float* __restrict__ rowinv,
    const unsigned* __restrict__ gmax, float* __restrict__ out)
{
    const int b = blockIdx.y;
    const int rowBase = blockIdx.x * 32;
    float* A = attn + (size_t)b * SS * SS;
    const unsigned short* Bv = vT + (size_t)b * DD * SS;   // [256][4096]
    const float bias = PIW * fdec(*gmax);

    __shared__ unsigned short As[32][APAD];
    __shared__ unsigned short Bs[256][APAD];

    const int tid = threadIdx.x;
    const int lane = tid & 63, w = tid >> 6;
    const int m = lane & 15, qq = lane >> 4;

    // A-staging assignment: thread handles rows ra, ra+16 at float4 chunk ch
    const int ch = tid & 15;
    const int ra = tid >> 4;
    float mr[2], ri[2];
    #pragma unroll
    for (int i = 0; i < 2; i++) {
        int rr = rowBase + ra + i * 16;
        mr[i] = rowm[b * SS + rr];
        ri[i] = rowinv[b * SS + rr];
    }

    f32x4 acc[2][4];
    #pragma unroll
    for (int i = 0; i < 2; i++)
        #pragma unroll
        for (int j = 0; j < 4; j++)
            acc[i][j] = (f32x4){0.f, 0.f, 0.f, 0.f};

    for (int k0 = 0; k0 < SS; k0 += 64) {
        // A: 32 rows x 64 raw fp32 -> softmax -> write fp32 + bf16 LDS
        #pragma unroll
        for (int i = 0; i < 2; i++) {
            int rr = rowBase + ra + i * 16;               // row within batch
            size_t off = (size_t)rr * SS + k0 + ch * 4;
            float4 t = *(const float4*)&A[off];
            int j0 = k0 + ch * 4;
            float e0 = t.x + ((j0 + 0 == rr) ? bias : 0.0f);
            float e1 = t.y + ((j0 + 1 == rr) ? bias : 0.0f);
            float e2 = t.z + ((j0 + 2 == rr) ? bias : 0.0f);
            float e3 = t.w + ((j0 + 3 == rr) ? bias : 0.0f);
            float w0 = __expf(e0 - mr[i]) * ri[i];
            float w1 = __expf(e1 - mr[i]) * ri[i];
            float w2 = __expf(e2 - mr[i]) * ri[i];
            float w3 = __expf(e3 - mr[i]) * ri[i];
            *(float4*)&A[off] = make_float4(w0, w1, w2, w3);
            *(u16v4*)&As[ra + i * 16][ch * 4] =
                (u16v4){f2bf(w0), f2bf(w1), f2bf(w2), f2bf(w3)};
        }
        // B: vT 256 rows x 64 bf16
        {
            const int chb = (tid & 7) * 8;
            #pragma unroll
            for (int i = 0; i < 8; i++) {
                int r = (tid >> 3) + i * 32;
                *(u16v8*)&Bs[r][chb] = *(const u16v8*)&Bv[(size_t)r * SS + k0 + chb];
            }
        }
        __syncthreads();

        #pragma unroll
        for (int kk = 0; kk < 64; kk += 32) {
            const int kb = kk + qq * 8;
            u16v8 af[2], bf[4];
            #pragma unroll
            for (int i = 0; i < 2; i++)
                af[i] = *(const u16v8*)&As[i * 16 + m][kb];
            #pragma unroll
            for (int j = 0; j < 4; j++)
                bf[j] = *(const u16v8*)&Bs[w * 64 + j * 16 + m][kb];
            #pragma unroll
            for (int i = 0; i < 2; i++)
                #pragma unroll
                for (int j = 0; j < 4; j++)
                    acc[i][j] = mfma_bf16(af[i], bf[j], acc[i][j]);
        }
        __syncthreads();
    }

    #pragma unroll
    for (int i = 0; i < 2; i++) {
        #pragma unroll
        for (int j = 0; j < 4; j++) {
            #pragma unroll
            for (int r = 0; r < 4; r++) {
                int row = rowBase + i * 16 + qq * 4 + r;
                int col = w * 64 + j * 16 + m;
                out[((size_t)b * SS + row) * DD + col] = acc[i][j][r];
            }
        }
    }
}

extern "C" void kernel_launch(void* const* d_in, const int* in_sizes, int n_in,
                              void* d_out, int out_size, void* d_ws, size_t ws_size,
                              hipStream_t stream)
{
    const float* query = (const float*)d_in[0];
    const float* key_  = (const float*)d_in[1];
    const float* value = (const float*)d_in[2];
    const float* Wq    = (const float*)d_in[3];
    const float* Wk    = (const float*)d_in[4];
    const float* Wv    = (const float*)d_in[5];

    float* out  = (float*)d_out;                          // [B,S,D]
    float* attn = out + (size_t)BB * SS * DD;             // [B,S,S]

    const size_t E = (size_t)BB * SS * DD;                // 4.19M elements
    unsigned short* qh = (unsigned short*)d_ws;
    unsigned short* ql = qh + E;
    unsigned short* kh = ql + E;
    unsigned short* kl = kh + E;
    unsigned short* vT = kl + E;
    float* tmaxg  = (float*)(vT + E);                     // [32][16384]
    float* tsumg  = tmaxg + 32 * (size_t)NROWS;           // [32][16384]
    float* rowm   = tsumg + 32 * (size_t)NROWS;           // [16384]
    float* rowinv = rowm + NROWS;                         // [16384]
    unsigned* gmax = (unsigned*)(rowinv + NROWS);

    // 1) projections: bf16 splits for q,k; transposed bf16 v; gmax init
    proj_kernel<<<dim3(DD / TN, (BB * SS) / TM, 3), 256, 0, stream>>>(
        query, key_, value, Wq, Wk, Wv, qh, ql, kh, kl, vT, gmax);
    // 2) raw scores via split-bf16 MFMA + per-row tile stats + global max
    scores_mfma<<<dim3(SS / 128, SS / 128, BB), 256, 0, stream>>>(
        qh, ql, kh, kl, attn, gmax, tmaxg, tsumg);
    // 3) merge tile stats -> per-row (max, 1/sum) with diag bias
    stats_merge<<<dim3(NROWS / 256), 256, 0, stream>>>(
        tmaxg, tsumg, attn, gmax, rowm, rowinv);
    // 4) fused softmax-normalize (writes fp32 attn output) + attn @ v
    av_softmax_mfma<<<dim3(SS / 32, BB), 256, 0, stream>>>(
        attn, vT, rowm, rowinv, gmax, out);
}

// Round 3
// 672.665 us; speedup vs baseline: 1.0845x; 1.0845x over previous
//
#include <hip/hip_runtime.h>
#include <cstdint>
#include <cstddef>

// Problem constants
#define BB 4
#define SS 4096
#define DD 256
#define SCORE_SCALE (1.0f/16.0f)   // 1/sqrt(256)
#define PIW 0.5f
#define NROWS (BB * SS)            // 16384 flattened rows

typedef float          f32x4  __attribute__((ext_vector_type(4)));
typedef __bf16         bf16v8 __attribute__((ext_vector_type(8)));
typedef unsigned short u16v8  __attribute__((ext_vector_type(8)));
typedef unsigned short u16v4  __attribute__((ext_vector_type(4)));

__device__ __forceinline__ f32x4 mfma_bf16(u16v8 a, u16v8 b, f32x4 c) {
    return __builtin_amdgcn_mfma_f32_16x16x32_bf16(
        __builtin_bit_cast(bf16v8, a), __builtin_bit_cast(bf16v8, b), c, 0, 0, 0);
}

__device__ __forceinline__ unsigned short f2bf(float f) {
    unsigned u = __float_as_uint(f);
    u += 0x7FFFu + ((u >> 16) & 1u);           // RNE (inputs finite)
    return (unsigned short)(u >> 16);
}
__device__ __forceinline__ float bf2f(unsigned short h) {
    return __uint_as_float(((unsigned)h) << 16);
}
__device__ __forceinline__ unsigned fenc(float x) {
    unsigned u = __float_as_uint(x);
    return (u & 0x80000000u) ? ~u : (u | 0x80000000u);
}
__device__ __forceinline__ float fdec(unsigned e) {
    return __uint_as_float((e & 0x80000000u) ? (e ^ 0x80000000u) : ~e);
}

// ---------------------------------------------------------------------------
// Projections (fp32 vector GEMM, precision-critical): C = A[16384,256]@W[256,256].
// z=0: qh/ql bf16 split. z=1: kh/kl split. z=2: vT bf16 transposed [B][D][S].
// Also inits gmax.
// ---------------------------------------------------------------------------
#define TM 128
#define TN 128
#define TK 16
#define PADW 132

__global__ __launch_bounds__(256) void proj_kernel(
    const float* __restrict__ query, const float* __restrict__ key_, const float* __restrict__ value,
    const float* __restrict__ Wq, const float* __restrict__ Wk, const float* __restrict__ Wv,
    unsigned short* __restrict__ qh, unsigned short* __restrict__ ql,
    unsigned short* __restrict__ kh, unsigned short* __restrict__ kl,
    unsigned short* __restrict__ vT, unsigned* __restrict__ gmax)
{
    const int z = blockIdx.z;
    const float* A = (z == 0) ? query : (z == 1) ? key_ : value;
    const float* W = (z == 0) ? Wq    : (z == 1) ? Wk   : Wv;
    if (z == 0 && blockIdx.x == 0 && blockIdx.y == 0 && threadIdx.x == 0)
        *gmax = 0x007FFFFFu;   // fenc(-inf)

    const int K = DD, N = DD;
    __shared__ float As[TK][PADW];
    __shared__ float Bs[TK][PADW];
    const int tid = threadIdx.x;
    const int tx = tid & 15, ty = tid >> 4;
    const int rowBase = blockIdx.y * TM;   // flattened B*S row
    const int colBase = blockIdx.x * TN;

    float acc[8][8] = {};

    for (int k0 = 0; k0 < K; k0 += TK) {
        #pragma unroll
        for (int i = 0; i < 2; i++) {
            int idx = tid + i * 256;
            int r = idx >> 2, kq = idx & 3;
            const float4 av = *(const float4*)&A[(size_t)(rowBase + r) * K + k0 + kq * 4];
            As[kq * 4 + 0][r] = av.x; As[kq * 4 + 1][r] = av.y;
            As[kq * 4 + 2][r] = av.z; As[kq * 4 + 3][r] = av.w;
        }
        #pragma unroll
        for (int i = 0; i < 2; i++) {
            int idx = tid + i * 256;
            int kk = idx >> 5, cq = idx & 31;
            *(float4*)&Bs[kk][cq * 4] = *(const float4*)&W[(size_t)(k0 + kk) * N + colBase + cq * 4];
        }
        __syncthreads();
        #pragma unroll
        for (int kk = 0; kk < TK; kk++) {
            float a[8], b[8];
            *(float4*)&a[0] = *(const float4*)&As[kk][ty * 8];
            *(float4*)&a[4] = *(const float4*)&As[kk][ty * 8 + 4];
            *(float4*)&b[0] = *(const float4*)&Bs[kk][tx * 8];
            *(float4*)&b[4] = *(const float4*)&Bs[kk][tx * 8 + 4];
            #pragma unroll
            for (int i = 0; i < 8; i++)
                #pragma unroll
                for (int j = 0; j < 8; j++)
                    acc[i][j] = fmaf(a[i], b[j], acc[i][j]);
        }
        __syncthreads();
    }

    #pragma unroll
    for (int i = 0; i < 8; i++) {
        const int gr = rowBase + ty * 8 + i;           // flattened B*S row
        if (z == 2) {
            const int b2 = gr >> 12, s2 = gr & (SS - 1);
            #pragma unroll
            for (int j = 0; j < 8; j++) {
                int col = colBase + tx * 8 + j;
                vT[((size_t)b2 * DD + col) * SS + s2] = f2bf(acc[i][j]);
            }
        } else {
            unsigned short h[8], l[8];
            #pragma unroll
            for (int j = 0; j < 8; j++) {
                h[j] = f2bf(acc[i][j]);
                l[j] = f2bf(acc[i][j] - bf2f(h[j]));
            }
            unsigned short* H = (z == 0) ? qh : kh;
            unsigned short* L = (z == 0) ? ql : kl;
            size_t base = (size_t)gr * DD + colBase + tx * 8;
            *(u16v4*)&H[base]     = (u16v4){h[0], h[1], h[2], h[3]};
            *(u16v4*)&H[base + 4] = (u16v4){h[4], h[5], h[6], h[7]};
            *(u16v4*)&L[base]     = (u16v4){l[0], l[1], l[2], l[3]};
            *(u16v4*)&L[base + 4] = (u16v4){l[4], l[5], l[6], l[7]};
        }
    }
}

// ---------------------------------------------------------------------------
// Scores: C = (q@k^T)/16 via split-bf16 MFMA: qh*kh + qh*kl + ql*kh.
// 128x128 C-tile, 4 waves (2x2 of 64x64), BK=32.
// Epilogue: per-row (max, sumexp) over this 128-col tile -> tmaxg/tsumg,
// plus block max -> gmax. All computed from register-resident acc.
// C stores are nontemporal (268 MB stream, re-read only much later).
// ---------------------------------------------------------------------------
#define SPAD 40   // 32 + 8 bf16 LDS row stride

__global__ __launch_bounds__(256) void scores_mfma(
    const unsigned short* __restrict__ qh, const unsigned short* __restrict__ ql,
    const unsigned short* __restrict__ kh, const unsigned short* __restrict__ kl,
    float* __restrict__ attn, unsigned* __restrict__ gmax,
    float* __restrict__ tmaxg, float* __restrict__ tsumg)
{
    const int b = blockIdx.z;
    const size_t boff = (size_t)b * SS * DD;
    const unsigned short* Qh = qh + boff;
    const unsigned short* Ql = ql + boff;
    const unsigned short* Kh = kh + boff;
    const unsigned short* Kl = kl + boff;
    float* C = attn + (size_t)b * SS * SS;

    __shared__ unsigned short Ah[128][SPAD];
    __shared__ unsigned short Al[128][SPAD];
    __shared__ unsigned short Bh[128][SPAD];
    __shared__ unsigned short Bl[128][SPAD];
    __shared__ float s_m[4][64];
    __shared__ float s_s[4][64];
    __shared__ float red[128];

    const int tid = threadIdx.x;
    const int lane = tid & 63, w = tid >> 6;
    const int wr = (w >> 1) * 64, wc = (w & 1) * 64;
    const int m = lane & 15, qq = lane >> 4;
    const int rowBase = blockIdx.y * 128;
    const int colBase = blockIdx.x * 128;

    f32x4 acc[4][4];
    #pragma unroll
    for (int i = 0; i < 4; i++)
        #pragma unroll
        for (int j = 0; j < 4; j++)
            acc[i][j] = (f32x4){0.f, 0.f, 0.f, 0.f};

    const int chunk = (tid & 3) * 8;        // bf16 offset within 32-wide k-slab
    const int srow  = tid >> 2;             // 0..63

    for (int k0 = 0; k0 < DD; k0 += 32) {
        #pragma unroll
        for (int i = 0; i < 2; i++) {
            int r = srow + i * 64;
            size_t ga = (size_t)(rowBase + r) * DD + k0 + chunk;
            size_t gb = (size_t)(colBase + r) * DD + k0 + chunk;
            *(u16v8*)&Ah[r][chunk] = *(const u16v8*)&Qh[ga];
            *(u16v8*)&Al[r][chunk] = *(const u16v8*)&Ql[ga];
            *(u16v8*)&Bh[r][chunk] = *(const u16v8*)&Kh[gb];
            *(u16v8*)&Bl[r][chunk] = *(const u16v8*)&Kl[gb];
        }
        __syncthreads();

        const int kb = qq * 8;
        u16v8 ah[4], al[4], bh[4], bl[4];
        #pragma unroll
        for (int i = 0; i < 4; i++) {
            ah[i] = *(const u16v8*)&Ah[wr + i * 16 + m][kb];
            al[i] = *(const u16v8*)&Al[wr + i * 16 + m][kb];
            bh[i] = *(const u16v8*)&Bh[wc + i * 16 + m][kb];
            bl[i] = *(const u16v8*)&Bl[wc + i * 16 + m][kb];
        }
        #pragma unroll
        for (int i = 0; i < 4; i++)
            #pragma unroll
            for (int j = 0; j < 4; j++) {
                acc[i][j] = mfma_bf16(ah[i], bh[j], acc[i][j]);
                acc[i][j] = mfma_bf16(ah[i], bl[j], acc[i][j]);
                acc[i][j] = mfma_bf16(al[i], bh[j], acc[i][j]);
            }
        __syncthreads();
    }

    // scale once; all consumers (C store, stats, gmax) use scaled values
    #pragma unroll
    for (int i = 0; i < 4; i++)
        #pragma unroll
        for (int j = 0; j < 4; j++)
            acc[i][j] *= SCORE_SCALE;

    // store raw scores (nontemporal: pure stream)
    #pragma unroll
    for (int i = 0; i < 4; i++)
        #pragma unroll
        for (int j = 0; j < 4; j++)
            #pragma unroll
            for (int r = 0; r < 4; r++) {
                int row = rowBase + wr + i * 16 + qq * 4 + r;
                int col = colBase + wc + j * 16 + m;
                __builtin_nontemporal_store(acc[i][j][r], &C[(size_t)row * SS + col]);
            }

    // ---- per-row tile stats (flash-style), register resident ----
    float lmax[16];
    #pragma unroll
    for (int i = 0; i < 4; i++)
        #pragma unroll
        for (int r = 0; r < 4; r++)
            lmax[i * 4 + r] = fmaxf(fmaxf(acc[i][0][r], acc[i][1][r]),
                                    fmaxf(acc[i][2][r], acc[i][3][r]));
    #pragma unroll
    for (int t = 0; t < 16; t++) {
        #pragma unroll
        for (int msk = 1; msk < 16; msk <<= 1)
            lmax[t] = fmaxf(lmax[t], __shfl_xor(lmax[t], msk));
    }
    if (m == 0) {
        #pragma unroll
        for (int i = 0; i < 4; i++)
            #pragma unroll
            for (int r = 0; r < 4; r++)
                s_m[w][i * 16 + qq * 4 + r] = lmax[i * 4 + r];
    }
    __syncthreads();
    float lsum[16];
    #pragma unroll
    for (int i = 0; i < 4; i++)
        #pragma unroll
        for (int r = 0; r < 4; r++) {
            int idx = i * 16 + qq * 4 + r;
            float rm = fmaxf(s_m[w][idx], s_m[w ^ 1][idx]);
            float s = 0.f;
            #pragma unroll
            for (int j = 0; j < 4; j++)
                s += __expf(acc[i][j][r] - rm);
            lsum[i * 4 + r] = s;
        }
    #pragma unroll
    for (int t = 0; t < 16; t++) {
        #pragma unroll
        for (int msk = 1; msk < 16; msk <<= 1)
            lsum[t] += __shfl_xor(lsum[t], msk);
    }
    if (m == 0) {
        #pragma unroll
        for (int i = 0; i < 4; i++)
            #pragma unroll
            for (int r = 0; r < 4; r++)
                s_s[w][i * 16 + qq * 4 + r] = lsum[i * 4 + r];
    }
    __syncthreads();

    if (tid < 128) {
        int wp = tid >> 6, lr = tid & 63;
        float tm = fmaxf(s_m[2 * wp][lr], s_m[2 * wp + 1][lr]);
        float ts = s_s[2 * wp][lr] + s_s[2 * wp + 1][lr];   // same reference max
        size_t gi = (size_t)blockIdx.x * NROWS + (size_t)b * SS + rowBase + tid;
        tmaxg[gi] = tm;
        tsumg[gi] = ts;
        red[tid] = tm;
    }
    __syncthreads();
    for (int s2 = 64; s2 > 0; s2 >>= 1) {
        if (tid < s2) red[tid] = fmaxf(red[tid], red[tid + s2]);
        __syncthreads();
    }
    if (tid == 0) atomicMax(gmax, fenc(red[0]));
}

// ---------------------------------------------------------------------------
// Merge per-tile stats into per-row (max, 1/sum), folding in the diag bias
// (needs final gmax). Reads 4 MB stats + 16K diag elements. Tiny.
// ---------------------------------------------------------------------------
__global__ __launch_bounds__(256) void stats_merge(
    const float* __restrict__ tmaxg, const float* __restrict__ tsumg,
    const float* __restrict__ attn, const unsigned* __restrict__ gmax,
    float* __restrict__ rowm, float* __restrict__ rowinv)
{
    const int grow = blockIdx.x * 256 + threadIdx.x;   // 0..16383
    const int b = grow >> 12, i = grow & (SS - 1);
    const float bias = PIW * fdec(*gmax);

    float tm[32];
    float mx = -INFINITY;
    #pragma unroll
    for (int t = 0; t < 32; t++) {
        tm[t] = tmaxg[(size_t)t * NROWS + grow];
        mx = fmaxf(mx, tm[t]);
    }
    const float dii = attn[(size_t)b * SS * SS + (size_t)i * SS + i];
    mx = fmaxf(mx, dii + bias);

    float s = 0.f;
    #pragma unroll
    for (int t = 0; t < 32; t++)
        s += tsumg[(size_t)t * NROWS + grow] * __expf(tm[t] - mx);
    // replace unbiased diag contribution with biased one
    s += __expf(dii + bias - mx) - __expf(dii - mx);

    rowm[grow] = mx;
    rowinv[grow] = 1.0f / s;
}

// ---------------------------------------------------------------------------
// Fused softmax + AV, MLP-oriented rewrite.
// BM=32, BN=256, BK=128. Grid: 512 blocks (1D) with XCD-aware decode so each
// batch's vT (2 MB) stays resident in one XCD-pair's L2. A (raw scores) is
// register-prefetched one K-step ahead (64 B/thread in flight), exp'd once,
// written back (nontemporal) and staged to a small double-buffered LDS tile.
// B fragments are read straight from L2 (no LDS staging). One sync per step.
// ---------------------------------------------------------------------------
__global__ __launch_bounds__(256) void av_softmax_mfma(
    float* __restrict__ attn, const unsigned short* __restrict__ vT,
    const float* __restrict__ rowm, const float* __restrict__ rowinv,
    const unsigned* __restrict__ gmax, float* __restrict__ out)
{
    // XCD-aware decode: linear block -> (batch, rowTile). block i lands on
    // XCD i%8; batch b owns XCDs {2b, 2b+1} so vT[b] is L2-resident there.
    const int lin = blockIdx.x;
    const int b = (lin & 7) >> 1;
    const int rowTile = ((lin >> 3) << 1) | (lin & 1);   // 0..127
    const int rowBase = rowTile * 32;

    float* A = attn + (size_t)b * SS * SS;
    const unsigned short* Bv = vT + (size_t)b * DD * SS;   // [256][4096]
    const float bias = PIW * fdec(*gmax);

    __shared__ unsigned short As[2][32][136];   // bf16 A tile, dbuf, +8 pad

    const int tid = threadIdx.x;
    const int lane = tid & 63, w = tid >> 6;
    const int m = lane & 15, qq = lane >> 4;

    // A-staging map: thread owns row ra, fp32 cols c0 + {0,32,64,96}
    const int ra = tid >> 3;              // 0..31
    const int c0 = (tid & 7) * 4;         // 0,4,...,28
    const int rr = rowBase + ra;
    float* Arow = A + (size_t)rr * SS;
    const float mr = rowm[b * SS + rr];
    const float ri = rowinv[b * SS + rr];

    // per-lane vT row bases (constant over k)
    const unsigned short* Bp[4];
    #pragma unroll
    for (int j = 0; j < 4; j++)
        Bp[j] = Bv + (size_t)(w * 64 + j * 16 + m) * SS;

    f32x4 acc[2][4];
    #pragma unroll
    for (int i = 0; i < 2; i++)
        #pragma unroll
        for (int j = 0; j < 4; j++)
            acc[i][j] = (f32x4){0.f, 0.f, 0.f, 0.f};

    f32x4 pf[4];

    auto loadA = [&](int kbase) {
        #pragma unroll
        for (int u = 0; u < 4; u++)
            pf[u] = __builtin_nontemporal_load(
                (const f32x4*)&Arow[kbase + c0 + u * 32]);
    };
    // exp-normalize pf, write fp32 weights back, stage bf16 into As[buf]
    auto procStore = [&](int kbase, int buf) {
        #pragma unroll
        for (int u = 0; u < 4; u++) {
            int c = c0 + u * 32;
            int j0 = kbase + c;
            float e0 = pf[u][0] + ((j0 + 0 == rr) ? bias : 0.0f);
            float e1 = pf[u][1] + ((j0 + 1 == rr) ? bias : 0.0f);
            float e2 = pf[u][2] + ((j0 + 2 == rr) ? bias : 0.0f);
            float e3 = pf[u][3] + ((j0 + 3 == rr) ? bias : 0.0f);
            float w0 = __expf(e0 - mr) * ri;
            float w1 = __expf(e1 - mr) * ri;
            float w2 = __expf(e2 - mr) * ri;
            float w3 = __expf(e3 - mr) * ri;
            f32x4 wv = (f32x4){w0, w1, w2, w3};
            __builtin_nontemporal_store(wv, (f32x4*)&Arow[j0]);
            *(u16v4*)&As[buf][ra][c] =
                (u16v4){f2bf(w0), f2bf(w1), f2bf(w2), f2bf(w3)};
        }
    };

    const int NT = SS / 128;   // 32 K-steps

    loadA(0);
    procStore(0, 0);
    __syncthreads();

    for (int t = 0; t < NT; t++) {
        const int k0 = t * 128;
        const int cur = t & 1;
        if (t + 1 < NT)
            loadA(k0 + 128);            // prefetch next A step (in flight
                                        // across the whole MFMA phase)
        #pragma unroll
        for (int kk = 0; kk < 4; kk++) {
            const int kb = kk * 32 + qq * 8;
            u16v8 bf_[4], af_[2];
            #pragma unroll
            for (int j = 0; j < 4; j++)
                bf_[j] = *(const u16v8*)&Bp[j][k0 + kb];   // L2-resident vT
            #pragma unroll
            for (int i = 0; i < 2; i++)
                af_[i] = *(const u16v8*)&As[cur][i * 16 + m][kb];
            #pragma unroll
            for (int i = 0; i < 2; i++)
                #pragma unroll
                for (int j = 0; j < 4; j++)
                    acc[i][j] = mfma_bf16(af_[i], bf_[j], acc[i][j]);
        }
        if (t + 1 < NT) {
            procStore(k0 + 128, cur ^ 1);
            __syncthreads();
        }
    }

    #pragma unroll
    for (int i = 0; i < 2; i++) {
        #pragma unroll
        for (int j = 0; j < 4; j++) {
            #pragma unroll
            for (int r = 0; r < 4; r++) {
                int row = rowBase + i * 16 + qq * 4 + r;
                int col = w * 64 + j * 16 + m;
                __builtin_nontemporal_store(
                    acc[i][j][r], &out[((size_t)b * SS + row) * DD + col]);
            }
        }
    }
}

extern "C" void kernel_launch(void* const* d_in, const int* in_sizes, int n_in,
                              void* d_out, int out_size, void* d_ws, size_t ws_size,
                              hipStream_t stream)
{
    const float* query = (const float*)d_in[0];
    const float* key_  = (const float*)d_in[1];
    const float* value = (const float*)d_in[2];
    const float* Wq    = (const float*)d_in[3];
    const float* Wk    = (const float*)d_in[4];
    const float* Wv    = (const float*)d_in[5];

    float* out  = (float*)d_out;                          // [B,S,D]
    float* attn = out + (size_t)BB * SS * DD;             // [B,S,S]

    const size_t E = (size_t)BB * SS * DD;                // 4.19M elements
    unsigned short* qh = (unsigned short*)d_ws;
    unsigned short* ql = qh + E;
    unsigned short* kh = ql + E;
    unsigned short* kl = kh + E;
    unsigned short* vT = kl + E;
    float* tmaxg  = (float*)(vT + E);                     // [32][16384]
    float* tsumg  = tmaxg + 32 * (size_t)NROWS;           // [32][16384]
    float* rowm   = tsumg + 32 * (size_t)NROWS;           // [16384]
    float* rowinv = rowm + NROWS;                         // [16384]
    unsigned* gmax = (unsigned*)(rowinv + NROWS);

    // 1) projections: bf16 splits for q,k; transposed bf16 v; gmax init
    proj_kernel<<<dim3(DD / TN, (BB * SS) / TM, 3), 256, 0, stream>>>(
        query, key_, value, Wq, Wk, Wv, qh, ql, kh, kl, vT, gmax);
    // 2) raw scores via split-bf16 MFMA + per-row tile stats + global max
    scores_mfma<<<dim3(SS / 128, SS / 128, BB), 256, 0, stream>>>(
        qh, ql, kh, kl, attn, gmax, tmaxg, tsumg);
    // 3) merge tile stats -> per-row (max, 1/sum) with diag bias
    stats_merge<<<dim3(NROWS / 256), 256, 0, stream>>>(
        tmaxg, tsumg, attn, gmax, rowm, rowinv);
    // 4) fused softmax-normalize (writes fp32 attn output) + attn @ v
    av_softmax_mfma<<<dim3(512), 256, 0, stream>>>(
        attn, vT, rowm, rowinv, gmax, out);
}